// Round 12
// baseline (259.521 us; speedup 1.0000x reference)
//
#include <hip/hip_runtime.h>
#include <hip/hip_fp16.h>
#include <math.h>

#define LSEQ   2048
#define DMODEL 512
#define NHEAD  8
#define DK     64
#define UK     38            // u = int(5*ln(2048)) = 38

typedef __attribute__((ext_vector_type(8))) _Float16 v8h;
typedef __attribute__((ext_vector_type(4))) _Float16 v4h;
typedef __attribute__((ext_vector_type(4))) float    v4f;
typedef __attribute__((ext_vector_type(8))) unsigned short v8us;

// order-preserving monotone maps (verified R2/R3)
__device__ __forceinline__ unsigned long long mapu64(double x){
    unsigned long long s = (unsigned long long)__double_as_longlong(x);
    return (s & 0x8000000000000000ull) ? ~s : (s | 0x8000000000000000ull);
}
__device__ __forceinline__ unsigned map32(float x){
    unsigned s = __float_as_uint(x);
    return (s & 0x80000000u) ? ~s : (s | 0x80000000u);
}
__device__ __forceinline__ float unmap32(unsigned u){
    unsigned s = (u & 0x80000000u) ? (u & 0x7fffffffu) : ~u;
    return __uint_as_float(s);
}
// u16 monotone map for raw half bits
__device__ __forceinline__ unsigned map16(unsigned h){
    return (h & 0x8000u) ? ((~h) & 0xFFFFu) : (h | 0x8000u);
}

// stage 8 f32 -> (hi, lo) fp16 v8h pair. Bit-identical to the old split_hl pass.
__device__ __forceinline__ void cvt8_hl(const float* __restrict__ src,
                                        v8h* __restrict__ h8, v8h* __restrict__ l8){
    float4 a = *(const float4*)src;
    float4 b = *(const float4*)(src + 4);
    v8h h, l;
    h[0] = (_Float16)a.x; l[0] = (_Float16)(a.x - (float)h[0]);
    h[1] = (_Float16)a.y; l[1] = (_Float16)(a.y - (float)h[1]);
    h[2] = (_Float16)a.z; l[2] = (_Float16)(a.z - (float)h[2]);
    h[3] = (_Float16)a.w; l[3] = (_Float16)(a.w - (float)h[3]);
    h[4] = (_Float16)b.x; l[4] = (_Float16)(b.x - (float)h[4]);
    h[5] = (_Float16)b.y; l[5] = (_Float16)(b.y - (float)h[5]);
    h[6] = (_Float16)b.z; l[6] = (_Float16)(b.z - (float)h[6]);
    h[7] = (_Float16)b.w; l[7] = (_Float16)(b.w - (float)h[7]);
    *h8 = h; *l8 = l;
}

// ------- fused Q/K/V projections via split-fp16 MFMA ------------------------------
// R26: reads X/W f32 directly, converting to (hi,lo) during LDS staging (values
// bit-identical to the old split_hl pre-pass; ~2us extra VALU grid-wide, saves
// the split kernel + 24MB HBM round-trip). MFMA core R18-proven.
__global__ __launch_bounds__(256) void qkv_f16(
    const float* __restrict__ X,  const float* __restrict__ Wq,
    const float* __restrict__ Wk, const float* __restrict__ Wv,
    const float* __restrict__ bq, const float* __restrict__ bk,
    const float* __restrict__ bv,
    double* __restrict__ qD, double* __restrict__ kRow,
    __half* __restrict__ qH, __half* __restrict__ kH, float* __restrict__ vB)
{
    const int mode = blockIdx.z;                 // 0 = Q, 1 = K, 2 = V
    const float* __restrict__ W    = (mode == 0) ? Wq : (mode == 1 ? Wk : Wv);
    const float* __restrict__ bias = (mode == 0) ? bq : (mode == 1 ? bk : bv);
    const int r0 = blockIdx.x * 64, c0 = blockIdx.y * 64;
    __shared__ _Float16 Ah[64][72], Al[64][72];  // +8 pad, row stride 144B
    __shared__ _Float16 Bh[64][72], Bl[64][72];
    const int tid  = threadIdx.x;
    const int lane = tid & 63, wv = tid >> 6;
    const int m0   = wv << 4;                    // wave's 16-row slice
    const int row  = lane & 15, kq = lane >> 4;

    v4f acc[4] = {};                             // 4 j-tiles of 16x16

    for (int kb = 0; kb < DMODEL; kb += 64){
        __syncthreads();
        #pragma unroll
        for (int it = 0; it < 2; ++it){
            int slot = it * 256 + tid;           // 512 v8h slots: 64 rows x 8
            int m = slot >> 3, o8 = (slot & 7) << 3;
            cvt8_hl(&X[(size_t)(r0 + m) * DMODEL + kb + o8],
                    (v8h*)&Ah[m][o8], (v8h*)&Al[m][o8]);
            cvt8_hl(&W[(size_t)(c0 + m) * DMODEL + kb + o8],
                    (v8h*)&Bh[m][o8], (v8h*)&Bl[m][o8]);
        }
        __syncthreads();
        v8h ah0 = *(const v8h*)&Ah[m0 + row][kq * 8];
        v8h ah1 = *(const v8h*)&Ah[m0 + row][kq * 8 + 32];
        v8h al0 = *(const v8h*)&Al[m0 + row][kq * 8];
        v8h al1 = *(const v8h*)&Al[m0 + row][kq * 8 + 32];
        #pragma unroll
        for (int j = 0; j < 4; ++j){
            const int j0 = j << 4;
            v8h bh0 = *(const v8h*)&Bh[j0 + row][kq * 8];
            v8h bh1 = *(const v8h*)&Bh[j0 + row][kq * 8 + 32];
            v8h bl0 = *(const v8h*)&Bl[j0 + row][kq * 8];
            v8h bl1 = *(const v8h*)&Bl[j0 + row][kq * 8 + 32];
            acc[j] = __builtin_amdgcn_mfma_f32_16x16x32_f16(ah0, bh0, acc[j], 0, 0, 0);
            acc[j] = __builtin_amdgcn_mfma_f32_16x16x32_f16(ah0, bl0, acc[j], 0, 0, 0);
            acc[j] = __builtin_amdgcn_mfma_f32_16x16x32_f16(al0, bh0, acc[j], 0, 0, 0);
            acc[j] = __builtin_amdgcn_mfma_f32_16x16x32_f16(ah1, bh1, acc[j], 0, 0, 0);
            acc[j] = __builtin_amdgcn_mfma_f32_16x16x32_f16(ah1, bl1, acc[j], 0, 0, 0);
            acc[j] = __builtin_amdgcn_mfma_f32_16x16x32_f16(al1, bh1, acc[j], 0, 0, 0);
        }
    }

    const int h = c0 >> 6;                       // 64-col block == one head
    #pragma unroll
    for (int j = 0; j < 4; ++j){
        const int dk = (j << 4) + row;
        const float bi = bias[c0 + dk];
        #pragma unroll
        for (int rr = 0; rr < 4; ++rr){
            const int r = r0 + m0 + (kq << 2) + rr;
            const int bidx = r >> 11, l = r & 2047;
            const size_t rowb = (size_t)(bidx * NHEAD + h) * LSEQ + l;
            float v = acc[j][rr] + bi;
            if (mode == 0){
                double vd = (double)v * 0.125;   // exact pow2 scale
                qD[rowb * DK + dk] = vd;
                ((_Float16*)qH)[rowb * DK + dk] = (_Float16)vd;
            } else if (mode == 1){
                kRow[rowb * DK + dk] = (double)v;
                ((_Float16*)kH)[rowb * DK + dk] = (_Float16)v;
            } else {
                vB[rowb * DK + dk] = v;
            }
        }
    }
}

// ------- O projection via split-f16 MFMA ------------------------------------------
// R26: reads ctx/Wo f32 directly, converting during staging (kills split_ctx).
__global__ __launch_bounds__(256) void o_proj(
    const float* __restrict__ ctx, const float* __restrict__ Wo,
    const float* __restrict__ bias, float* __restrict__ out)
{
    const int r0 = blockIdx.x * 64, c0 = blockIdx.y * 64;
    __shared__ _Float16 Ah[64][72], Al[64][72];
    __shared__ _Float16 Bh[64][72], Bl[64][72];
    const int tid  = threadIdx.x;
    const int lane = tid & 63, wv = tid >> 6;
    const int m0   = wv << 4;
    const int row  = lane & 15, kq = lane >> 4;

    v4f acc[4] = {};

    for (int kb = 0; kb < DMODEL; kb += 64){
        __syncthreads();
        #pragma unroll
        for (int it = 0; it < 2; ++it){
            int slot = it * 256 + tid;
            int m = slot >> 3, o8 = (slot & 7) << 3;
            cvt8_hl(&ctx[(size_t)(r0 + m) * DMODEL + kb + o8],
                    (v8h*)&Ah[m][o8], (v8h*)&Al[m][o8]);
            cvt8_hl(&Wo[(size_t)(c0 + m) * DMODEL + kb + o8],
                    (v8h*)&Bh[m][o8], (v8h*)&Bl[m][o8]);
        }
        __syncthreads();
        v8h ah0 = *(const v8h*)&Ah[m0 + row][kq * 8];
        v8h ah1 = *(const v8h*)&Ah[m0 + row][kq * 8 + 32];
        v8h al0 = *(const v8h*)&Al[m0 + row][kq * 8];
        v8h al1 = *(const v8h*)&Al[m0 + row][kq * 8 + 32];
        #pragma unroll
        for (int j = 0; j < 4; ++j){
            const int j0 = j << 4;
            v8h bh0 = *(const v8h*)&Bh[j0 + row][kq * 8];
            v8h bh1 = *(const v8h*)&Bh[j0 + row][kq * 8 + 32];
            v8h bl0 = *(const v8h*)&Bl[j0 + row][kq * 8];
            v8h bl1 = *(const v8h*)&Bl[j0 + row][kq * 8 + 32];
            acc[j] = __builtin_amdgcn_mfma_f32_16x16x32_f16(ah0, bh0, acc[j], 0, 0, 0);
            acc[j] = __builtin_amdgcn_mfma_f32_16x16x32_f16(ah0, bl0, acc[j], 0, 0, 0);
            acc[j] = __builtin_amdgcn_mfma_f32_16x16x32_f16(al0, bh0, acc[j], 0, 0, 0);
            acc[j] = __builtin_amdgcn_mfma_f32_16x16x32_f16(ah1, bh1, acc[j], 0, 0, 0);
            acc[j] = __builtin_amdgcn_mfma_f32_16x16x32_f16(ah1, bl1, acc[j], 0, 0, 0);
            acc[j] = __builtin_amdgcn_mfma_f32_16x16x32_f16(al1, bh1, acc[j], 0, 0, 0);
        }
    }

    #pragma unroll
    for (int j = 0; j < 4; ++j){
        const int dk = (j << 4) + row;
        const float bi = bias[c0 + dk];
        #pragma unroll
        for (int rr = 0; rr < 4; ++rr){
            const int r = r0 + m0 + (kq << 2) + rr;
            out[(size_t)r * DMODEL + c0 + dk] = acc[j][rr] + bi;
        }
    }
}

// ---------------- f32 GEMM: O projection (fallback path only) ---------------------
__global__ __launch_bounds__(256) void gemm_f32(
    const float* __restrict__ X, const float* __restrict__ W,
    const float* __restrict__ bias, float* __restrict__ out)
{
    const int r0 = blockIdx.x * 64, c0 = blockIdx.y * 64;
    __shared__ float Xs[32][68];
    __shared__ float Ws[32][68];
    const int tid = threadIdx.x;
    const int tx = tid & 15, ty = tid >> 4;
    float acc[4][4] = {};
    for (int kb = 0; kb < DMODEL; kb += 32){
        __syncthreads();
        #pragma unroll
        for (int i = 0; i < 2; ++i){
            int f4 = i * 256 + tid;
            int m = f4 >> 3, kg = (f4 & 7) << 2;
            float4 xv = *(const float4*)&X[(r0 + m) * DMODEL + kb + kg];
            Xs[kg+0][m] = xv.x; Xs[kg+1][m] = xv.y; Xs[kg+2][m] = xv.z; Xs[kg+3][m] = xv.w;
            float4 wv = *(const float4*)&W[(c0 + m) * DMODEL + kb + kg];
            Ws[kg+0][m] = wv.x; Ws[kg+1][m] = wv.y; Ws[kg+2][m] = wv.z; Ws[kg+3][m] = wv.w;
        }
        __syncthreads();
        #pragma unroll
        for (int kk = 0; kk < 32; ++kk){
            float4 av = *(const float4*)&Xs[kk][ty << 2];
            float4 bv = *(const float4*)&Ws[kk][tx << 2];
            float a[4] = {av.x, av.y, av.z, av.w};
            float b[4] = {bv.x, bv.y, bv.z, bv.w};
            #pragma unroll
            for (int ii = 0; ii < 4; ++ii)
                #pragma unroll
                for (int jj = 0; jj < 4; ++jj)
                    acc[ii][jj] = fmaf(a[ii], b[jj], acc[ii][jj]);
        }
    }
    #pragma unroll
    for (int ii = 0; ii < 4; ++ii){
        int r = r0 + (ty << 2) + ii;
        float4 o;
        o.x = acc[ii][0] + bias[c0 + (tx << 2) + 0];
        o.y = acc[ii][1] + bias[c0 + (tx << 2) + 1];
        o.z = acc[ii][2] + bias[c0 + (tx << 2) + 2];
        o.w = acc[ii][3] + bias[c0 + (tx << 2) + 3];
        *(float4*)&out[(size_t)r * DMODEL + c0 + (tx << 2)] = o;
    }
}

// ------- score GEMM slab via MFMA from pre-converted fp16 Q/K ---------------------
// R25-proven: 128x128 tile, LDS-staged coalesced ushort8 stores.
__global__ __launch_bounds__(256) void score_gemm(
    const __half* __restrict__ qH, const __half* __restrict__ kH,
    __half* __restrict__ Sh, const int bh0)
{
    const int bh = bh0 + blockIdx.z;
    const int r0 = blockIdx.x * 128, c0 = blockIdx.y * 128;
    __shared__ _Float16 smem[2 * 128 * 72];              // 36.9 KB, dual-purpose
    _Float16 (*Qs)[72] = (_Float16(*)[72])smem;
    _Float16 (*Ks)[72] = (_Float16(*)[72])(smem + 128 * 72);
    unsigned short (*Cs)[136] = (unsigned short(*)[136])smem;  // 17408 u16 <= 18432
    const int tid = threadIdx.x;
    const int lane = tid & 63, wv = tid >> 6;
    const size_t qb = ((size_t)bh * LSEQ + r0) * DK;
    const size_t kb = ((size_t)bh * LSEQ + c0) * DK;
    #pragma unroll
    for (int i = 0; i < 4; ++i){
        int c = i * 256 + tid;           // 1024 v8h slots: 128 rows x 8
        int m = c >> 3, off8 = (c & 7) << 3;
        *(v8h*)&Qs[m][off8] = *(const v8h*)&qH[qb + (size_t)m * DK + off8];
        *(v8h*)&Ks[m][off8] = *(const v8h*)&kH[kb + (size_t)m * DK + off8];
    }
    __syncthreads();
    const int m0 = (wv >> 1) << 6;       // wave's 64-row slice: 0 or 64
    const int n0 = (wv & 1) << 6;        // wave's 64-col slice: 0 or 64
    const int row = lane & 15, kq = lane >> 4;
    v8h a0[4], a1[4], b0[4], b1[4];
    #pragma unroll
    for (int r = 0; r < 4; ++r){
        a0[r] = *(const v8h*)&Qs[m0 + r*16 + row][kq * 8];
        a1[r] = *(const v8h*)&Qs[m0 + r*16 + row][kq * 8 + 32];
    }
    #pragma unroll
    for (int c = 0; c < 4; ++c){
        b0[c] = *(const v8h*)&Ks[n0 + c*16 + row][kq * 8];
        b1[c] = *(const v8h*)&Ks[n0 + c*16 + row][kq * 8 + 32];
    }
    __syncthreads();                     // all frags in regs; safe to reuse smem
    #pragma unroll
    for (int r = 0; r < 4; ++r){
        #pragma unroll
        for (int c = 0; c < 4; ++c){
            v4f acc = {0.f, 0.f, 0.f, 0.f};
            acc = __builtin_amdgcn_mfma_f32_16x16x32_f16(a0[r], b0[c], acc, 0, 0, 0);
            acc = __builtin_amdgcn_mfma_f32_16x16x32_f16(a1[r], b1[c], acc, 0, 0, 0);
            #pragma unroll
            for (int i = 0; i < 4; ++i){
                Cs[m0 + r*16 + kq*4 + i][n0 + c*16 + row] =
                    (unsigned short)__half_as_ushort((__half)acc[i]);
            }
        }
    }
    __syncthreads();
    // coalesced writeout: 2048 ushort8 groups (128 rows x 16), 8 per thread
    unsigned short* __restrict__ dst =
        (unsigned short*)Sh + ((size_t)blockIdx.z * LSEQ + r0) * LSEQ + c0;
    #pragma unroll
    for (int g0 = 0; g0 < 8; ++g0){
        int g = g0 * 256 + tid;
        int rr = g >> 4, cg = (g & 15) << 3;
        *(v8us*)&dst[(size_t)rr * LSEQ + cg] = *(const v8us*)&Cs[rr][cg];
    }
}

// ---- shared tail: candidates -> exact f64 recheck -> exact top-38 -> softmax/AV --
// R18-proven (absmax 0.0039). DO NOT TOUCH.
__device__ __forceinline__ void finish_common(
    const int ncand, const int gl, const int bh, const int lane,
    const double qd, const double* __restrict__ kRow, const float* __restrict__ vB,
    float* __restrict__ ctx, int* __restrict__ jlsR, float* __restrict__ wlsR,
    double* __restrict__ sLds)
{
    const unsigned long long mlt = (1ull << lane) - 1ull;
    if (lane >= ncand) jlsR[lane] = 0;
    if (lane < 4) jlsR[64 + lane] = 0;
    int myJ = jlsR[lane];

    // exact f64 recheck: 8 lanes per candidate, 8 candidates per pass
    double q8[8];
    #pragma unroll
    for (int k = 0; k < 8; ++k) q8[k] = __shfl(qd, (lane & 7) + (k << 3));
    const int grp = lane >> 3, dl = lane & 7;
    const size_t kb = (size_t)bh * LSEQ;
    for (int e0 = 0; e0 < ncand; e0 += 8){
        int j = jlsR[e0 + grp];
        const double* __restrict__ kr = &kRow[(kb + j) * DK + dl];
        double s = 0.0;
        #pragma unroll
        for (int k = 0; k < 8; ++k) s = fma(q8[k], kr[k << 3], s);
        s += __shfl_xor(s, 1); s += __shfl_xor(s, 2); s += __shfl_xor(s, 4);
        if (dl == 0) sLds[e0 + grp] = s;
    }
    double myS = (lane < ncand) ? sLds[lane] : -1.0e308;

    // exact top-38 among candidates
    unsigned long long cu = (lane < ncand) ? mapu64(myS) : 0ull;
    unsigned long long T64 = 0ull;
    for (int bit = 63; bit >= 0; --bit){
        unsigned long long Tp = T64 | (1ull << bit);
        int c = __popcll(__ballot(cu >= Tp));
        if (c >= UK){ T64 = Tp; if (c == UK) break; }
    }
    const bool sel = (cu >= T64);              // ties kept, matching reference mask

    double xm = sel ? myS : -1.0e308;
    #pragma unroll
    for (int off = 32; off; off >>= 1) xm = fmax(xm, __shfl_xor(xm, off));
    float w = sel ? expf((float)(myS - xm)) : 0.0f;
    float z = w;
    #pragma unroll
    for (int off = 32; off; off >>= 1) z += __shfl_xor(z, off);
    unsigned long long bm = __ballot(sel);
    int p = __popcll(bm & mlt);
    if (sel){ wlsR[p] = w; jlsR[p] = myJ; }
    const int cnt = __popcll(bm);
    const float invZ = 1.0f / z;

    if (lane >= cnt) wlsR[lane] = 0.0f;
    if (lane < 4){ wlsR[64 + lane] = 0.0f; jlsR[64 + lane] = 0; }

    const float* __restrict__ vsl = vB + (size_t)bh * (LSEQ * DK);
    float o = 0.0f;
    for (int e = 0; e < cnt; e += 4){
        float w0 = wlsR[e],   w1 = wlsR[e+1], w2 = wlsR[e+2], w3 = wlsR[e+3];
        int   j0 = jlsR[e],   j1 = jlsR[e+1], j2 = jlsR[e+2], j3 = jlsR[e+3];
        float v0 = vsl[(size_t)j0 * DK + lane];
        float v1 = vsl[(size_t)j1 * DK + lane];
        float v2 = vsl[(size_t)j2 * DK + lane];
        float v3 = vsl[(size_t)j3 * DK + lane];
        o = fmaf(w0, v0, o); o = fmaf(w1, v1, o);
        o = fmaf(w2, v2, o); o = fmaf(w3, v3, o);
    }
    ctx[((size_t)(bh >> 3) * LSEQ + gl) * DMODEL + (bh & 7) * DK + lane] = o * invZ;
}

// ---- fallback-path row tail (f32 keys) -------------------------------------------
__device__ __forceinline__ void finish_row_f32(
    float (&acc)[32], const int gl, const int bh, const int lane, const float margin,
    const double qd, const double* __restrict__ kRow, const float* __restrict__ vB,
    float* __restrict__ ctx, int* __restrict__ jlsR, float* __restrict__ wlsR,
    double* __restrict__ sLds)
{
    unsigned u[32];
    #pragma unroll
    for (int ch = 0; ch < 32; ++ch) u[ch] = map32(acc[ch]);
    unsigned T = 0u; int curc = 2048;
    for (int bit = 31; bit >= 0; --bit){
        unsigned Tp = T | (1u << bit);
        int c = 0;
        #pragma unroll
        for (int ch = 0; ch < 32; ++ch) c += __popcll(__ballot(u[ch] >= Tp));
        if (c >= UK){ T = Tp; curc = c; }
        if (curc <= 48) break;
    }
    const unsigned Tlo = map32(unmap32(T) - margin);
    const unsigned long long mlt = (1ull << lane) - 1ull;
    int base = 0;
    #pragma unroll
    for (int ch = 0; ch < 32; ++ch){
        bool sel = (u[ch] >= Tlo);
        unsigned long long bm = __ballot(sel);
        int p = base + __popcll(bm & mlt);
        if (sel && p < 64) jlsR[p] = (ch << 6) + lane;
        base += __popcll(bm);
    }
    const int ncand = base > 64 ? 64 : base;
    finish_common(ncand, gl, bh, lane, qd, kRow, vB, ctx, jlsR, wlsR, sLds);
}

// ---------------- selection from fp16 S slab: u16 keys, one wave per row ----------
// R18-proven version (109.6us). DO NOT TOUCH (R19/R20/R23 all regressed it).
__global__ __launch_bounds__(256) void select_kernel(
    const __half* __restrict__ Sh, const double* __restrict__ qD,
    const double* __restrict__ kRow, const float* __restrict__ vB,
    float* __restrict__ ctx, const int bh0)
{
    __shared__ int    jls[4][68];
    __shared__ float  wls[4][68];
    __shared__ double sds[4][64];
    const int tid = threadIdx.x, lane = tid & 63, wv = tid >> 6;
    const int rgS = blockIdx.x * 4 + wv;
    const int bh = bh0 + (rgS >> 11), l = rgS & 2047;
    const double qd = qD[((size_t)bh * LSEQ + l) * DK + lane];
    unsigned u[32];                      // u16 monotone keys of the 32 owned scores
    const unsigned short* __restrict__ Srow =
        (const unsigned short*)Sh + (size_t)rgS * LSEQ;
    #pragma unroll
    for (int it = 0; it < 4; ++it){
        uint4 v = *(const uint4*)&Srow[it * 512 + (lane << 3)];
        unsigned ws[4] = {v.x, v.y, v.z, v.w};
        #pragma unroll
        for (int q = 0; q < 4; ++q){
            u[it*8 + 2*q]     = map16(ws[q] & 0xFFFFu);
            u[it*8 + 2*q + 1] = map16(ws[q] >> 16);
        }
    }
    // 16-bit bitsearch: T = exact 38th-largest fp16 key
    unsigned T = 0u; int curc = 2048;
    for (int bit = 15; bit >= 0; --bit){
        unsigned Tp = T | (1u << bit);
        int c = 0;
        #pragma unroll
        for (int ch = 0; ch < 32; ++ch) c += __popcll(__ballot(u[ch] >= Tp));
        if (c >= UK){ T = Tp; curc = c; }
        if (curc <= 48) break;
    }
    // threshold minus margin, conservatively rounded down -> superset candidates
    unsigned hb = (T & 0x8000u) ? (T & 0x7FFFu) : ((~T) & 0xFFFFu);
    float tf = __half2float(__ushort_as_half((unsigned short)hb)) - 2.2e-2f;
    unsigned short tlb = __half_as_ushort(__float2half_rd(tf));
    const unsigned Tlo = map16(tlb);

    const unsigned long long mlt = (1ull << lane) - 1ull;
    int base = 0;
    #pragma unroll
    for (int ch = 0; ch < 32; ++ch){
        bool sel = (u[ch] >= Tlo);
        unsigned long long bm = __ballot(sel);
        int p = base + __popcll(bm & mlt);
        int j = ((ch >> 3) << 9) + (lane << 3) + (ch & 7);
        if (sel && p < 64) jls[wv][p] = j;
        base += __popcll(bm);
    }
    const int ncand = base > 64 ? 64 : base;
    finish_common(ncand, l, bh, lane, qd, kRow, vB, ctx,
                  &jls[wv][0], &wls[wv][0], &sds[wv][0]);
}

// ---------------- fallback fused attention (R3/R4, proven) ------------------------
__global__ __launch_bounds__(256) void attn_kernel(
    const double* __restrict__ qD, const double* __restrict__ kRow,
    const float* __restrict__ vB, float* __restrict__ ctx)
{
    __shared__ float2 Kld2[16 * 66];
    __shared__ float  qsf[8][64];
    __shared__ int    jls[8][68];
    __shared__ float  wlsf[8][68];
    __shared__ double sds[8][64];

    const int tid = threadIdx.x, lane = tid & 63, wv = tid >> 6;
    const int bh = blockIdx.x >> 8;
    const int l0 = (blockIdx.x & 255) << 3;
    const int rA = l0 + (wv << 1), rB = rA + 1;

    for (int e = tid; e < 512; e += 256){
        int r = e >> 6, d = e & 63;
        qsf[r][d] = (float)qD[((size_t)bh * LSEQ + l0 + r) * DK + d];
    }
    const double qdA = qD[((size_t)bh * LSEQ + rA) * DK + lane];
    const double qdB = qD[((size_t)bh * LSEQ + rB) * DK + lane];

    float accA[32] = {}, accB[32] = {};
    const size_t kBase = (size_t)bh * (LSEQ * DK);

    for (int dh = 0; dh < 2; ++dh){
        __syncthreads();
        float qa[32], qb[32];
        #pragma unroll
        for (int i = 0; i < 8; ++i){
            float4 va = *(const float4*)&qsf[wv << 1][dh * 32 + i * 4];
            qa[i*4+0]=va.x; qa[i*4+1]=va.y; qa[i*4+2]=va.z; qa[i*4+3]=va.w;
            float4 vb4 = *(const float4*)&qsf[(wv << 1) + 1][dh * 32 + i * 4];
            qb[i*4+0]=vb4.x; qb[i*4+1]=vb4.y; qb[i*4+2]=vb4.z; qb[i*4+3]=vb4.w;
        }
        #pragma unroll
        for (int ch = 0; ch < 32; ++ch){
            const int cb = ch << 6;
            __syncthreads();
            #pragma unroll
            for (int i = 0; i < 4; ++i){
                int j   = i * 16 + (wv << 2) + (lane >> 4);
                int dpl = lane & 15;
                double2 kd = *(const double2*)&kRow[kBase + (size_t)(cb + j) * DK + dh * 32 + dpl * 2];
                Kld2[dpl * 66 + j] = make_float2((float)kd.x, (float)kd.y);
            }
            __syncthreads();
            float a0 = accA[ch], b0 = accB[ch];
            #pragma unroll
            for (int dpl = 0; dpl < 16; ++dpl){
                float2 k = Kld2[dpl * 66 + lane];
                a0 = fmaf(qa[2*dpl],   k.x, a0);
                a0 = fmaf(qa[2*dpl+1], k.y, a0);
                b0 = fmaf(qb[2*dpl],   k.x, b0);
                b0 = fmaf(qb[2*dpl+1], k.y, b0);
            }
            accA[ch] = a0; accB[ch] = b0;
        }
    }

    finish_row_f32(accA, rA, bh, lane, 1e-3f, qdA, kRow, vB, ctx,
                   &jls[wv<<1][0], &wlsf[wv<<1][0], &sds[wv<<1][0]);
    finish_row_f32(accB, rB, bh, lane, 1e-3f, qdB, kRow, vB, ctx,
                   &jls[(wv<<1)+1][0], &wlsf[(wv<<1)+1][0], &sds[(wv<<1)+1][0]);
}

extern "C" void kernel_launch(void* const* d_in, const int* in_sizes, int n_in,
                              void* d_out, int out_size, void* d_ws, size_t ws_size,
                              hipStream_t stream)
{
    const float* x  = (const float*)d_in[0];
    const float* Wq = (const float*)d_in[1];
    const float* bq = (const float*)d_in[2];
    const float* Wk = (const float*)d_in[3];
    const float* bk = (const float*)d_in[4];
    const float* Wv = (const float*)d_in[5];
    const float* bv = (const float*)d_in[6];
    const float* Wo = (const float*)d_in[7];
    const float* bo = (const float*)d_in[8];
    float* out = (float*)d_out;
    char* ws = (char*)d_ws;
    const size_t MiB = 1024 * 1024;
    // fixed: qD 16 | kRow 16 | vB 8 | ctx 8 | qH 4 | kH 4  (56 MiB); Sh slab after.
    // R26: no aliased scratch anymore (splits fused into consumers).
    double* qD   = (double*)(ws);
    double* kRow = (double*)(ws + 16 * MiB);
    float*  vB   = (float*) (ws + 32 * MiB);
    float*  ctx  = (float*) (ws + 40 * MiB);
    __half* qH   = (__half*)(ws + 48 * MiB);
    __half* kH   = (__half*)(ws + 52 * MiB);
    __half* Sh   = (__half*)(ws + 56 * MiB);
    size_t avail = (ws_size > 56 * MiB) ? (ws_size - 56 * MiB) : 0;
    int slab = (int)(avail / (8 * MiB)); if (slab > 16) slab = 16;

    dim3 blk(256);
    qkv_f16<<<dim3(64, 8, 3), blk, 0, stream>>>(x, Wq, Wk, Wv, bq, bk, bv,
                                                qD, kRow, qH, kH, vB);
    if (slab >= 1){
        for (int s0 = 0; s0 < NHEAD * 2; s0 += slab){
            int nb = NHEAD * 2 - s0; if (nb > slab) nb = slab;
            score_gemm   <<<dim3(16, 16, nb), blk, 0, stream>>>(qH, kH, Sh, s0);
            select_kernel<<<dim3(nb * 512),   blk, 0, stream>>>(Sh, qD, kRow, vB, ctx, s0);
        }
        o_proj<<<dim3(64, 8), blk, 0, stream>>>(ctx, Wo, bo, out);
    } else {
        attn_kernel<<<dim3(4096), blk, 0, stream>>>(qD, kRow, vB, ctx);
        gemm_f32<<<dim3(64, 8), blk, 0, stream>>>(ctx, Wo, bo, out);
    }
}

// Round 13
// 250.454 us; speedup vs baseline: 1.0362x; 1.0362x over previous
//
#include <hip/hip_runtime.h>
#include <hip/hip_fp16.h>
#include <math.h>

#define LSEQ   2048
#define DMODEL 512
#define NHEAD  8
#define DK     64
#define UK     38            // u = int(5*ln(2048)) = 38

typedef __attribute__((ext_vector_type(8))) _Float16 v8h;
typedef __attribute__((ext_vector_type(4))) _Float16 v4h;
typedef __attribute__((ext_vector_type(4))) float    v4f;
typedef __attribute__((ext_vector_type(8))) unsigned short v8us;

// order-preserving monotone maps (verified R2/R3)
__device__ __forceinline__ unsigned long long mapu64(double x){
    unsigned long long s = (unsigned long long)__double_as_longlong(x);
    return (s & 0x8000000000000000ull) ? ~s : (s | 0x8000000000000000ull);
}
__device__ __forceinline__ unsigned map32(float x){
    unsigned s = __float_as_uint(x);
    return (s & 0x80000000u) ? ~s : (s | 0x80000000u);
}
__device__ __forceinline__ float unmap32(unsigned u){
    unsigned s = (u & 0x80000000u) ? (u & 0x7fffffffu) : ~u;
    return __uint_as_float(s);
}
// u16 monotone map for raw half bits
__device__ __forceinline__ unsigned map16(unsigned h){
    return (h & 0x8000u) ? ((~h) & 0xFFFFu) : (h | 0x8000u);
}

// ------- split pass: f32 -> (hi, lo) fp16 pairs for X, Wq, Wk, Wv ----------------
// R27: standalone split restored (R26's in-consumer fusion put the convert VALU
// on qkv's barrier-bound critical path, +6.6us; the round trip here is L2/L3-
// absorbed and nearly free).
__global__ __launch_bounds__(256) void split_hl(
    const float* __restrict__ X,  const float* __restrict__ Wq,
    const float* __restrict__ Wk, const float* __restrict__ Wv,
    _Float16* __restrict__ Xh, _Float16* __restrict__ Xl,
    _Float16* __restrict__ Whl)          // [mode][Wh 262144 | Wl 262144]
{
    const int idx = blockIdx.x * 256 + threadIdx.x;      // float4-quad index
    const int NXQ = (4096 * 512) / 4;                    // 524288
    const float* __restrict__ src;
    _Float16* __restrict__ dh;
    _Float16* __restrict__ dl;
    size_t off;
    if (idx < NXQ){
        src = X; dh = Xh; dl = Xl; off = (size_t)idx * 4;
    } else {
        int wi = idx - NXQ;                              // 0 .. 3*65536-1
        int m  = wi >> 16;                               // which W
        src = (m == 0) ? Wq : (m == 1 ? Wk : Wv);
        dh  = Whl + (size_t)m * 524288;
        dl  = dh + 262144;
        off = (size_t)(wi & 65535) * 4;
    }
    float4 v = *(const float4*)&src[off];
    v4h h, l;
    h[0] = (_Float16)v.x; l[0] = (_Float16)(v.x - (float)h[0]);
    h[1] = (_Float16)v.y; l[1] = (_Float16)(v.y - (float)h[1]);
    h[2] = (_Float16)v.z; l[2] = (_Float16)(v.z - (float)h[2]);
    h[3] = (_Float16)v.w; l[3] = (_Float16)(v.w - (float)h[3]);
    *(v4h*)&dh[off] = h;
    *(v4h*)&dl[off] = l;
}

// ------- split pass for ctx and Wo (runs after select; buffers alias dead regions)
__global__ __launch_bounds__(256) void split_ctx(
    const float* __restrict__ ctx, const float* __restrict__ Wo,
    _Float16* __restrict__ Ch, _Float16* __restrict__ Cl,
    _Float16* __restrict__ WoH, _Float16* __restrict__ WoL)
{
    const int idx = blockIdx.x * 256 + threadIdx.x;      // float4-quad index
    const int NCQ = (4096 * 512) / 4;                    // 524288
    const float* __restrict__ src;
    _Float16* __restrict__ dh;
    _Float16* __restrict__ dl;
    size_t off;
    if (idx < NCQ){
        src = ctx; dh = Ch; dl = Cl; off = (size_t)idx * 4;
    } else {
        src = Wo; dh = WoH; dl = WoL;
        off = (size_t)(idx - NCQ) * 4;                   // 65536 quads
    }
    float4 v = *(const float4*)&src[off];
    v4h h, l;
    h[0] = (_Float16)v.x; l[0] = (_Float16)(v.x - (float)h[0]);
    h[1] = (_Float16)v.y; l[1] = (_Float16)(v.y - (float)h[1]);
    h[2] = (_Float16)v.z; l[2] = (_Float16)(v.z - (float)h[2]);
    h[3] = (_Float16)v.w; l[3] = (_Float16)(v.w - (float)h[3]);
    *(v4h*)&dh[off] = h;
    *(v4h*)&dl[off] = l;
}

// ------- fused Q/K/V projections via split-fp16 MFMA (R18-proven) -----------------
__global__ __launch_bounds__(256) void qkv_f16(
    const _Float16* __restrict__ Xh, const _Float16* __restrict__ Xl,
    const _Float16* __restrict__ Whl,
    const float* __restrict__ bq, const float* __restrict__ bk,
    const float* __restrict__ bv,
    double* __restrict__ qD, double* __restrict__ kRow,
    __half* __restrict__ qH, __half* __restrict__ kH, float* __restrict__ vB)
{
    const int mode = blockIdx.z;                 // 0 = Q, 1 = K, 2 = V
    const _Float16* __restrict__ Wh = Whl + (size_t)mode * 524288;
    const _Float16* __restrict__ Wl = Wh + 262144;
    const float* __restrict__ bias = (mode == 0) ? bq : (mode == 1 ? bk : bv);
    const int r0 = blockIdx.x * 64, c0 = blockIdx.y * 64;
    __shared__ _Float16 Ah[64][72], Al[64][72];  // +8 pad, row stride 144B
    __shared__ _Float16 Bh[64][72], Bl[64][72];
    const int tid  = threadIdx.x;
    const int lane = tid & 63, wv = tid >> 6;
    const int m0   = wv << 4;                    // wave's 16-row slice
    const int row  = lane & 15, kq = lane >> 4;

    v4f acc[4] = {};                             // 4 j-tiles of 16x16

    for (int kb = 0; kb < DMODEL; kb += 64){
        __syncthreads();
        #pragma unroll
        for (int it = 0; it < 2; ++it){
            int slot = it * 256 + tid;           // 512 v8h slots: 64 rows x 8
            int m = slot >> 3, o8 = (slot & 7) << 3;
            size_t ga = (size_t)(r0 + m) * DMODEL + kb + o8;
            size_t gb = (size_t)(c0 + m) * DMODEL + kb + o8;
            *(v8h*)&Ah[m][o8] = *(const v8h*)&Xh[ga];
            *(v8h*)&Al[m][o8] = *(const v8h*)&Xl[ga];
            *(v8h*)&Bh[m][o8] = *(const v8h*)&Wh[gb];
            *(v8h*)&Bl[m][o8] = *(const v8h*)&Wl[gb];
        }
        __syncthreads();
        v8h ah0 = *(const v8h*)&Ah[m0 + row][kq * 8];
        v8h ah1 = *(const v8h*)&Ah[m0 + row][kq * 8 + 32];
        v8h al0 = *(const v8h*)&Al[m0 + row][kq * 8];
        v8h al1 = *(const v8h*)&Al[m0 + row][kq * 8 + 32];
        #pragma unroll
        for (int j = 0; j < 4; ++j){
            const int j0 = j << 4;
            v8h bh0 = *(const v8h*)&Bh[j0 + row][kq * 8];
            v8h bh1 = *(const v8h*)&Bh[j0 + row][kq * 8 + 32];
            v8h bl0 = *(const v8h*)&Bl[j0 + row][kq * 8];
            v8h bl1 = *(const v8h*)&Bl[j0 + row][kq * 8 + 32];
            acc[j] = __builtin_amdgcn_mfma_f32_16x16x32_f16(ah0, bh0, acc[j], 0, 0, 0);
            acc[j] = __builtin_amdgcn_mfma_f32_16x16x32_f16(ah0, bl0, acc[j], 0, 0, 0);
            acc[j] = __builtin_amdgcn_mfma_f32_16x16x32_f16(al0, bh0, acc[j], 0, 0, 0);
            acc[j] = __builtin_amdgcn_mfma_f32_16x16x32_f16(ah1, bh1, acc[j], 0, 0, 0);
            acc[j] = __builtin_amdgcn_mfma_f32_16x16x32_f16(ah1, bl1, acc[j], 0, 0, 0);
            acc[j] = __builtin_amdgcn_mfma_f32_16x16x32_f16(al1, bh1, acc[j], 0, 0, 0);
        }
    }

    const int h = c0 >> 6;                       // 64-col block == one head
    #pragma unroll
    for (int j = 0; j < 4; ++j){
        const int dk = (j << 4) + row;
        const float bi = bias[c0 + dk];
        #pragma unroll
        for (int rr = 0; rr < 4; ++rr){
            const int r = r0 + m0 + (kq << 2) + rr;
            const int bidx = r >> 11, l = r & 2047;
            const size_t rowb = (size_t)(bidx * NHEAD + h) * LSEQ + l;
            float v = acc[j][rr] + bi;
            if (mode == 0){
                double vd = (double)v * 0.125;   // exact pow2 scale
                qD[rowb * DK + dk] = vd;
                ((_Float16*)qH)[rowb * DK + dk] = (_Float16)vd;
            } else if (mode == 1){
                kRow[rowb * DK + dk] = (double)v;
                ((_Float16*)kH)[rowb * DK + dk] = (_Float16)v;
            } else {
                vB[rowb * DK + dk] = v;
            }
        }
    }
}

// ------- O projection via split-f16 MFMA (R25-proven) -----------------------------
__global__ __launch_bounds__(256) void o_proj(
    const _Float16* __restrict__ Ch, const _Float16* __restrict__ Cl,
    const _Float16* __restrict__ WoH, const _Float16* __restrict__ WoL,
    const float* __restrict__ bias, float* __restrict__ out)
{
    const int r0 = blockIdx.x * 64, c0 = blockIdx.y * 64;
    __shared__ _Float16 Ah[64][72], Al[64][72];
    __shared__ _Float16 Bh[64][72], Bl[64][72];
    const int tid  = threadIdx.x;
    const int lane = tid & 63, wv = tid >> 6;
    const int m0   = wv << 4;
    const int row  = lane & 15, kq = lane >> 4;

    v4f acc[4] = {};

    for (int kb = 0; kb < DMODEL; kb += 64){
        __syncthreads();
        #pragma unroll
        for (int it = 0; it < 2; ++it){
            int slot = it * 256 + tid;
            int m = slot >> 3, o8 = (slot & 7) << 3;
            size_t ga = (size_t)(r0 + m) * DMODEL + kb + o8;
            size_t gb = (size_t)(c0 + m) * DMODEL + kb + o8;
            *(v8h*)&Ah[m][o8] = *(const v8h*)&Ch[ga];
            *(v8h*)&Al[m][o8] = *(const v8h*)&Cl[ga];
            *(v8h*)&Bh[m][o8] = *(const v8h*)&WoH[gb];
            *(v8h*)&Bl[m][o8] = *(const v8h*)&WoL[gb];
        }
        __syncthreads();
        v8h ah0 = *(const v8h*)&Ah[m0 + row][kq * 8];
        v8h ah1 = *(const v8h*)&Ah[m0 + row][kq * 8 + 32];
        v8h al0 = *(const v8h*)&Al[m0 + row][kq * 8];
        v8h al1 = *(const v8h*)&Al[m0 + row][kq * 8 + 32];
        #pragma unroll
        for (int j = 0; j < 4; ++j){
            const int j0 = j << 4;
            v8h bh0 = *(const v8h*)&Bh[j0 + row][kq * 8];
            v8h bh1 = *(const v8h*)&Bh[j0 + row][kq * 8 + 32];
            v8h bl0 = *(const v8h*)&Bl[j0 + row][kq * 8];
            v8h bl1 = *(const v8h*)&Bl[j0 + row][kq * 8 + 32];
            acc[j] = __builtin_amdgcn_mfma_f32_16x16x32_f16(ah0, bh0, acc[j], 0, 0, 0);
            acc[j] = __builtin_amdgcn_mfma_f32_16x16x32_f16(ah0, bl0, acc[j], 0, 0, 0);
            acc[j] = __builtin_amdgcn_mfma_f32_16x16x32_f16(al0, bh0, acc[j], 0, 0, 0);
            acc[j] = __builtin_amdgcn_mfma_f32_16x16x32_f16(ah1, bh1, acc[j], 0, 0, 0);
            acc[j] = __builtin_amdgcn_mfma_f32_16x16x32_f16(ah1, bl1, acc[j], 0, 0, 0);
            acc[j] = __builtin_amdgcn_mfma_f32_16x16x32_f16(al1, bh1, acc[j], 0, 0, 0);
        }
    }

    #pragma unroll
    for (int j = 0; j < 4; ++j){
        const int dk = (j << 4) + row;
        const float bi = bias[c0 + dk];
        #pragma unroll
        for (int rr = 0; rr < 4; ++rr){
            const int r = r0 + m0 + (kq << 2) + rr;
            out[(size_t)r * DMODEL + c0 + dk] = acc[j][rr] + bi;
        }
    }
}

// ---------------- f32 GEMM: O projection (fallback path only) ---------------------
__global__ __launch_bounds__(256) void gemm_f32(
    const float* __restrict__ X, const float* __restrict__ W,
    const float* __restrict__ bias, float* __restrict__ out)
{
    const int r0 = blockIdx.x * 64, c0 = blockIdx.y * 64;
    __shared__ float Xs[32][68];
    __shared__ float Ws[32][68];
    const int tid = threadIdx.x;
    const int tx = tid & 15, ty = tid >> 4;
    float acc[4][4] = {};
    for (int kb = 0; kb < DMODEL; kb += 32){
        __syncthreads();
        #pragma unroll
        for (int i = 0; i < 2; ++i){
            int f4 = i * 256 + tid;
            int m = f4 >> 3, kg = (f4 & 7) << 2;
            float4 xv = *(const float4*)&X[(r0 + m) * DMODEL + kb + kg];
            Xs[kg+0][m] = xv.x; Xs[kg+1][m] = xv.y; Xs[kg+2][m] = xv.z; Xs[kg+3][m] = xv.w;
            float4 wv = *(const float4*)&W[(c0 + m) * DMODEL + kb + kg];
            Ws[kg+0][m] = wv.x; Ws[kg+1][m] = wv.y; Ws[kg+2][m] = wv.z; Ws[kg+3][m] = wv.w;
        }
        __syncthreads();
        #pragma unroll
        for (int kk = 0; kk < 32; ++kk){
            float4 av = *(const float4*)&Xs[kk][ty << 2];
            float4 bv = *(const float4*)&Ws[kk][tx << 2];
            float a[4] = {av.x, av.y, av.z, av.w};
            float b[4] = {bv.x, bv.y, bv.z, bv.w};
            #pragma unroll
            for (int ii = 0; ii < 4; ++ii)
                #pragma unroll
                for (int jj = 0; jj < 4; ++jj)
                    acc[ii][jj] = fmaf(a[ii], b[jj], acc[ii][jj]);
        }
    }
    #pragma unroll
    for (int ii = 0; ii < 4; ++ii){
        int r = r0 + (ty << 2) + ii;
        float4 o;
        o.x = acc[ii][0] + bias[c0 + (tx << 2) + 0];
        o.y = acc[ii][1] + bias[c0 + (tx << 2) + 1];
        o.z = acc[ii][2] + bias[c0 + (tx << 2) + 2];
        o.w = acc[ii][3] + bias[c0 + (tx << 2) + 3];
        *(float4*)&out[(size_t)r * DMODEL + c0 + (tx << 2)] = o;
    }
}

// ------- score GEMM slab via MFMA from pre-converted fp16 Q/K ---------------------
// R25-proven: 128x128 tile, LDS-staged coalesced ushort8 stores.
__global__ __launch_bounds__(256) void score_gemm(
    const __half* __restrict__ qH, const __half* __restrict__ kH,
    __half* __restrict__ Sh, const int bh0)
{
    const int bh = bh0 + blockIdx.z;
    const int r0 = blockIdx.x * 128, c0 = blockIdx.y * 128;
    __shared__ _Float16 smem[2 * 128 * 72];              // 36.9 KB, dual-purpose
    _Float16 (*Qs)[72] = (_Float16(*)[72])smem;
    _Float16 (*Ks)[72] = (_Float16(*)[72])(smem + 128 * 72);
    unsigned short (*Cs)[136] = (unsigned short(*)[136])smem;  // 17408 u16 <= 18432
    const int tid = threadIdx.x;
    const int lane = tid & 63, wv = tid >> 6;
    const size_t qb = ((size_t)bh * LSEQ + r0) * DK;
    const size_t kb = ((size_t)bh * LSEQ + c0) * DK;
    #pragma unroll
    for (int i = 0; i < 4; ++i){
        int c = i * 256 + tid;           // 1024 v8h slots: 128 rows x 8
        int m = c >> 3, off8 = (c & 7) << 3;
        *(v8h*)&Qs[m][off8] = *(const v8h*)&qH[qb + (size_t)m * DK + off8];
        *(v8h*)&Ks[m][off8] = *(const v8h*)&kH[kb + (size_t)m * DK + off8];
    }
    __syncthreads();
    const int m0 = (wv >> 1) << 6;       // wave's 64-row slice: 0 or 64
    const int n0 = (wv & 1) << 6;        // wave's 64-col slice: 0 or 64
    const int row = lane & 15, kq = lane >> 4;
    v8h a0[4], a1[4], b0[4], b1[4];
    #pragma unroll
    for (int r = 0; r < 4; ++r){
        a0[r] = *(const v8h*)&Qs[m0 + r*16 + row][kq * 8];
        a1[r] = *(const v8h*)&Qs[m0 + r*16 + row][kq * 8 + 32];
    }
    #pragma unroll
    for (int c = 0; c < 4; ++c){
        b0[c] = *(const v8h*)&Ks[n0 + c*16 + row][kq * 8];
        b1[c] = *(const v8h*)&Ks[n0 + c*16 + row][kq * 8 + 32];
    }
    __syncthreads();                     // all frags in regs; safe to reuse smem
    #pragma unroll
    for (int r = 0; r < 4; ++r){
        #pragma unroll
        for (int c = 0; c < 4; ++c){
            v4f acc = {0.f, 0.f, 0.f, 0.f};
            acc = __builtin_amdgcn_mfma_f32_16x16x32_f16(a0[r], b0[c], acc, 0, 0, 0);
            acc = __builtin_amdgcn_mfma_f32_16x16x32_f16(a1[r], b1[c], acc, 0, 0, 0);
            #pragma unroll
            for (int i = 0; i < 4; ++i){
                Cs[m0 + r*16 + kq*4 + i][n0 + c*16 + row] =
                    (unsigned short)__half_as_ushort((__half)acc[i]);
            }
        }
    }
    __syncthreads();
    // coalesced writeout: 2048 ushort8 groups (128 rows x 16), 8 per thread
    unsigned short* __restrict__ dst =
        (unsigned short*)Sh + ((size_t)blockIdx.z * LSEQ + r0) * LSEQ + c0;
    #pragma unroll
    for (int g0 = 0; g0 < 8; ++g0){
        int g = g0 * 256 + tid;
        int rr = g >> 4, cg = (g & 15) << 3;
        *(v8us*)&dst[(size_t)rr * LSEQ + cg] = *(const v8us*)&Cs[rr][cg];
    }
}

// ---- shared tail: candidates -> exact f64 recheck -> exact top-38 -> softmax/AV --
// R18-proven (absmax 0.0039). DO NOT TOUCH.
__device__ __forceinline__ void finish_common(
    const int ncand, const int gl, const int bh, const int lane,
    const double qd, const double* __restrict__ kRow, const float* __restrict__ vB,
    float* __restrict__ ctx, int* __restrict__ jlsR, float* __restrict__ wlsR,
    double* __restrict__ sLds)
{
    const unsigned long long mlt = (1ull << lane) - 1ull;
    if (lane >= ncand) jlsR[lane] = 0;
    if (lane < 4) jlsR[64 + lane] = 0;
    int myJ = jlsR[lane];

    // exact f64 recheck: 8 lanes per candidate, 8 candidates per pass
    double q8[8];
    #pragma unroll
    for (int k = 0; k < 8; ++k) q8[k] = __shfl(qd, (lane & 7) + (k << 3));
    const int grp = lane >> 3, dl = lane & 7;
    const size_t kb = (size_t)bh * LSEQ;
    for (int e0 = 0; e0 < ncand; e0 += 8){
        int j = jlsR[e0 + grp];
        const double* __restrict__ kr = &kRow[(kb + j) * DK + dl];
        double s = 0.0;
        #pragma unroll
        for (int k = 0; k < 8; ++k) s = fma(q8[k], kr[k << 3], s);
        s += __shfl_xor(s, 1); s += __shfl_xor(s, 2); s += __shfl_xor(s, 4);
        if (dl == 0) sLds[e0 + grp] = s;
    }
    double myS = (lane < ncand) ? sLds[lane] : -1.0e308;

    // exact top-38 among candidates
    unsigned long long cu = (lane < ncand) ? mapu64(myS) : 0ull;
    unsigned long long T64 = 0ull;
    for (int bit = 63; bit >= 0; --bit){
        unsigned long long Tp = T64 | (1ull << bit);
        int c = __popcll(__ballot(cu >= Tp));
        if (c >= UK){ T64 = Tp; if (c == UK) break; }
    }
    const bool sel = (cu >= T64);              // ties kept, matching reference mask

    double xm = sel ? myS : -1.0e308;
    #pragma unroll
    for (int off = 32; off; off >>= 1) xm = fmax(xm, __shfl_xor(xm, off));
    float w = sel ? expf((float)(myS - xm)) : 0.0f;
    float z = w;
    #pragma unroll
    for (int off = 32; off; off >>= 1) z += __shfl_xor(z, off);
    unsigned long long bm = __ballot(sel);
    int p = __popcll(bm & mlt);
    if (sel){ wlsR[p] = w; jlsR[p] = myJ; }
    const int cnt = __popcll(bm);
    const float invZ = 1.0f / z;

    if (lane >= cnt) wlsR[lane] = 0.0f;
    if (lane < 4){ wlsR[64 + lane] = 0.0f; jlsR[64 + lane] = 0; }

    const float* __restrict__ vsl = vB + (size_t)bh * (LSEQ * DK);
    float o = 0.0f;
    for (int e = 0; e < cnt; e += 4){
        float w0 = wlsR[e],   w1 = wlsR[e+1], w2 = wlsR[e+2], w3 = wlsR[e+3];
        int   j0 = jlsR[e],   j1 = jlsR[e+1], j2 = jlsR[e+2], j3 = jlsR[e+3];
        float v0 = vsl[(size_t)j0 * DK + lane];
        float v1 = vsl[(size_t)j1 * DK + lane];
        float v2 = vsl[(size_t)j2 * DK + lane];
        float v3 = vsl[(size_t)j3 * DK + lane];
        o = fmaf(w0, v0, o); o = fmaf(w1, v1, o);
        o = fmaf(w2, v2, o); o = fmaf(w3, v3, o);
    }
    ctx[((size_t)(bh >> 3) * LSEQ + gl) * DMODEL + (bh & 7) * DK + lane] = o * invZ;
}

// ---- fallback-path row tail (f32 keys) -------------------------------------------
__device__ __forceinline__ void finish_row_f32(
    float (&acc)[32], const int gl, const int bh, const int lane, const float margin,
    const double qd, const double* __restrict__ kRow, const float* __restrict__ vB,
    float* __restrict__ ctx, int* __restrict__ jlsR, float* __restrict__ wlsR,
    double* __restrict__ sLds)
{
    unsigned u[32];
    #pragma unroll
    for (int ch = 0; ch < 32; ++ch) u[ch] = map32(acc[ch]);
    unsigned T = 0u; int curc = 2048;
    for (int bit = 31; bit >= 0; --bit){
        unsigned Tp = T | (1u << bit);
        int c = 0;
        #pragma unroll
        for (int ch = 0; ch < 32; ++ch) c += __popcll(__ballot(u[ch] >= Tp));
        if (c >= UK){ T = Tp; curc = c; }
        if (curc <= 48) break;
    }
    const unsigned Tlo = map32(unmap32(T) - margin);
    const unsigned long long mlt = (1ull << lane) - 1ull;
    int base = 0;
    #pragma unroll
    for (int ch = 0; ch < 32; ++ch){
        bool sel = (u[ch] >= Tlo);
        unsigned long long bm = __ballot(sel);
        int p = base + __popcll(bm & mlt);
        if (sel && p < 64) jlsR[p] = (ch << 6) + lane;
        base += __popcll(bm);
    }
    const int ncand = base > 64 ? 64 : base;
    finish_common(ncand, gl, bh, lane, qd, kRow, vB, ctx, jlsR, wlsR, sLds);
}

// ---------------- selection from fp16 S slab: u16 keys, one wave per row ----------
// R18-proven version (109.6us). DO NOT TOUCH (R19/R20/R23 all regressed it).
__global__ __launch_bounds__(256) void select_kernel(
    const __half* __restrict__ Sh, const double* __restrict__ qD,
    const double* __restrict__ kRow, const float* __restrict__ vB,
    float* __restrict__ ctx, const int bh0)
{
    __shared__ int    jls[4][68];
    __shared__ float  wls[4][68];
    __shared__ double sds[4][64];
    const int tid = threadIdx.x, lane = tid & 63, wv = tid >> 6;
    const int rgS = blockIdx.x * 4 + wv;
    const int bh = bh0 + (rgS >> 11), l = rgS & 2047;
    const double qd = qD[((size_t)bh * LSEQ + l) * DK + lane];
    unsigned u[32];                      // u16 monotone keys of the 32 owned scores
    const unsigned short* __restrict__ Srow =
        (const unsigned short*)Sh + (size_t)rgS * LSEQ;
    #pragma unroll
    for (int it = 0; it < 4; ++it){
        uint4 v = *(const uint4*)&Srow[it * 512 + (lane << 3)];
        unsigned ws[4] = {v.x, v.y, v.z, v.w};
        #pragma unroll
        for (int q = 0; q < 4; ++q){
            u[it*8 + 2*q]     = map16(ws[q] & 0xFFFFu);
            u[it*8 + 2*q + 1] = map16(ws[q] >> 16);
        }
    }
    // 16-bit bitsearch: T = exact 38th-largest fp16 key
    unsigned T = 0u; int curc = 2048;
    for (int bit = 15; bit >= 0; --bit){
        unsigned Tp = T | (1u << bit);
        int c = 0;
        #pragma unroll
        for (int ch = 0; ch < 32; ++ch) c += __popcll(__ballot(u[ch] >= Tp));
        if (c >= UK){ T = Tp; curc = c; }
        if (curc <= 48) break;
    }
    // threshold minus margin, conservatively rounded down -> superset candidates
    unsigned hb = (T & 0x8000u) ? (T & 0x7FFFu) : ((~T) & 0xFFFFu);
    float tf = __half2float(__ushort_as_half((unsigned short)hb)) - 2.2e-2f;
    unsigned short tlb = __half_as_ushort(__float2half_rd(tf));
    const unsigned Tlo = map16(tlb);

    const unsigned long long mlt = (1ull << lane) - 1ull;
    int base = 0;
    #pragma unroll
    for (int ch = 0; ch < 32; ++ch){
        bool sel = (u[ch] >= Tlo);
        unsigned long long bm = __ballot(sel);
        int p = base + __popcll(bm & mlt);
        int j = ((ch >> 3) << 9) + (lane << 3) + (ch & 7);
        if (sel && p < 64) jls[wv][p] = j;
        base += __popcll(bm);
    }
    const int ncand = base > 64 ? 64 : base;
    finish_common(ncand, l, bh, lane, qd, kRow, vB, ctx,
                  &jls[wv][0], &wls[wv][0], &sds[wv][0]);
}

// ---------------- fallback fused attention (R3/R4, proven) ------------------------
__global__ __launch_bounds__(256) void attn_kernel(
    const double* __restrict__ qD, const double* __restrict__ kRow,
    const float* __restrict__ vB, float* __restrict__ ctx)
{
    __shared__ float2 Kld2[16 * 66];
    __shared__ float  qsf[8][64];
    __shared__ int    jls[8][68];
    __shared__ float  wlsf[8][68];
    __shared__ double sds[8][64];

    const int tid = threadIdx.x, lane = tid & 63, wv = tid >> 6;
    const int bh = blockIdx.x >> 8;
    const int l0 = (blockIdx.x & 255) << 3;
    const int rA = l0 + (wv << 1), rB = rA + 1;

    for (int e = tid; e < 512; e += 256){
        int r = e >> 6, d = e & 63;
        qsf[r][d] = (float)qD[((size_t)bh * LSEQ + l0 + r) * DK + d];
    }
    const double qdA = qD[((size_t)bh * LSEQ + rA) * DK + lane];
    const double qdB = qD[((size_t)bh * LSEQ + rB) * DK + lane];

    float accA[32] = {}, accB[32] = {};
    const size_t kBase = (size_t)bh * (LSEQ * DK);

    for (int dh = 0; dh < 2; ++dh){
        __syncthreads();
        float qa[32], qb[32];
        #pragma unroll
        for (int i = 0; i < 8; ++i){
            float4 va = *(const float4*)&qsf[wv << 1][dh * 32 + i * 4];
            qa[i*4+0]=va.x; qa[i*4+1]=va.y; qa[i*4+2]=va.z; qa[i*4+3]=va.w;
            float4 vb4 = *(const float4*)&qsf[(wv << 1) + 1][dh * 32 + i * 4];
            qb[i*4+0]=vb4.x; qb[i*4+1]=vb4.y; qb[i*4+2]=vb4.z; qb[i*4+3]=vb4.w;
        }
        #pragma unroll
        for (int ch = 0; ch < 32; ++ch){
            const int cb = ch << 6;
            __syncthreads();
            #pragma unroll
            for (int i = 0; i < 4; ++i){
                int j   = i * 16 + (wv << 2) + (lane >> 4);
                int dpl = lane & 15;
                double2 kd = *(const double2*)&kRow[kBase + (size_t)(cb + j) * DK + dh * 32 + dpl * 2];
                Kld2[dpl * 66 + j] = make_float2((float)kd.x, (float)kd.y);
            }
            __syncthreads();
            float a0 = accA[ch], b0 = accB[ch];
            #pragma unroll
            for (int dpl = 0; dpl < 16; ++dpl){
                float2 k = Kld2[dpl * 66 + lane];
                a0 = fmaf(qa[2*dpl],   k.x, a0);
                a0 = fmaf(qa[2*dpl+1], k.y, a0);
                b0 = fmaf(qb[2*dpl],   k.x, b0);
                b0 = fmaf(qb[2*dpl+1], k.y, b0);
            }
            accA[ch] = a0; accB[ch] = b0;
        }
    }

    finish_row_f32(accA, rA, bh, lane, 1e-3f, qdA, kRow, vB, ctx,
                   &jls[wv<<1][0], &wlsf[wv<<1][0], &sds[wv<<1][0]);
    finish_row_f32(accB, rB, bh, lane, 1e-3f, qdB, kRow, vB, ctx,
                   &jls[(wv<<1)+1][0], &wlsf[(wv<<1)+1][0], &sds[(wv<<1)+1][0]);
}

extern "C" void kernel_launch(void* const* d_in, const int* in_sizes, int n_in,
                              void* d_out, int out_size, void* d_ws, size_t ws_size,
                              hipStream_t stream)
{
    const float* x  = (const float*)d_in[0];
    const float* Wq = (const float*)d_in[1];
    const float* bq = (const float*)d_in[2];
    const float* Wk = (const float*)d_in[3];
    const float* bk = (const float*)d_in[4];
    const float* Wv = (const float*)d_in[5];
    const float* bv = (const float*)d_in[6];
    const float* Wo = (const float*)d_in[7];
    const float* bo = (const float*)d_in[8];
    float* out = (float*)d_out;
    char* ws = (char*)d_ws;
    const size_t MiB = 1024 * 1024;
    // fixed: qD 16 | kRow 16 | vB 8 | ctx 8 | qH 4 | kH 4  (56 MiB); Sh slab after.
    // Aliased scratch (all stream-ordered, no live-range overlap):
    //   Xh/Xl (split of X)      -> ctx region   (consumed by qkv before ctx write)
    //   Whl (Wq/Wk/Wv splits)   -> Sh head      (consumed before score writes Sh)
    //   Ch/Cl (split of ctx)    -> qH/kH region (qH/kH dead after score_gemm)
    //   WoH/WoL (split of Wo)   -> Sh head      (Sh dead after select)
    double* qD   = (double*)(ws);
    double* kRow = (double*)(ws + 16 * MiB);
    float*  vB   = (float*) (ws + 32 * MiB);
    float*  ctx  = (float*) (ws + 40 * MiB);
    __half* qH   = (__half*)(ws + 48 * MiB);
    __half* kH   = (__half*)(ws + 52 * MiB);
    __half* Sh   = (__half*)(ws + 56 * MiB);
    _Float16* Xh  = (_Float16*)(ws + 40 * MiB);   // 4 MiB (aliases ctx)
    _Float16* Xl  = (_Float16*)(ws + 44 * MiB);   // 4 MiB (aliases ctx)
    _Float16* Whl = (_Float16*)(ws + 56 * MiB);   // 3 MiB (aliases Sh head)
    _Float16* Ch  = (_Float16*)(ws + 48 * MiB);   // 4 MiB (aliases dead qH)
    _Float16* Cl  = (_Float16*)(ws + 52 * MiB);   // 4 MiB (aliases dead kH)
    _Float16* WoH = (_Float16*)(ws + 56 * MiB);   // 512 KB (aliases dead Sh)
    _Float16* WoL = (_Float16*)(ws + 56 * MiB + 512 * 1024);
    size_t avail = (ws_size > 56 * MiB) ? (ws_size - 56 * MiB) : 0;
    int slab = (int)(avail / (8 * MiB)); if (slab > 16) slab = 16;

    dim3 blk(256);
    split_hl<<<dim3(2816), blk, 0, stream>>>(x, Wq, Wk, Wv, Xh, Xl, Whl);
    qkv_f16 <<<dim3(64, 8, 3), blk, 0, stream>>>(Xh, Xl, Whl, bq, bk, bv,
                                                 qD, kRow, qH, kH, vB);
    if (slab >= 1){
        for (int s0 = 0; s0 < NHEAD * 2; s0 += slab){
            int nb = NHEAD * 2 - s0; if (nb > slab) nb = slab;
            score_gemm   <<<dim3(16, 16, nb), blk, 0, stream>>>(qH, kH, Sh, s0);
            select_kernel<<<dim3(nb * 512),   blk, 0, stream>>>(Sh, qD, kRow, vB, ctx, s0);
        }
        split_ctx<<<dim3(2304), blk, 0, stream>>>(ctx, Wo, Ch, Cl, WoH, WoL);
        o_proj  <<<dim3(64, 8), blk, 0, stream>>>(Ch, Cl, WoH, WoL, bo, out);
    } else {
        attn_kernel<<<dim3(4096), blk, 0, stream>>>(qD, kRow, vB, ctx);
        gemm_f32<<<dim3(64, 8), blk, 0, stream>>>(ctx, Wo, bo, out);
    }
}